// Round 1
// baseline (113.843 us; speedup 1.0000x reference)
//
#include <hip/hip_runtime.h>
#include <hip/hip_bf16.h>
#include <stdint.h>

typedef __attribute__((ext_vector_type(8))) short short8;
typedef __attribute__((ext_vector_type(4))) float f32x4;

#define NB 8
#define NN 2048
#define CC 256
#define LP1 4097
#define HR 192
#define PDim 16
#define KP 256
#define NPAD 448
#define HEAD_SCALE 0.17677669529663689f  /* 1/sqrt(32) */

// ---------------- K0: prep ----------------
// builds xb (16384 x 256 bf16) = folded x, WT (448 x 256 bf16, Q-part pre-scaled),
// and zero-fills P/R K-padding cols [208,256).
__global__ __launch_bounds__(256) void k0_prep(
    const float* __restrict__ feats,
    const float* __restrict__ Wq, const float* __restrict__ Wk,
    const float* __restrict__ Wpi, const float* __restrict__ Wpj,
    const float* __restrict__ Wd,
    __hip_bfloat16* __restrict__ xb, __hip_bfloat16* __restrict__ WT,
    unsigned* __restrict__ Ppad, unsigned* __restrict__ Rpad)
{
    const int XBN  = NB*NN*CC;      // 4194304
    const int WTN  = NPAD*CC;       // 114688
    const int PADN = NB*NN*24;      // 393216 uint32 per array (cols 208..255)
    const int TOT  = XBN + WTN + 2*PADN;
    int stride = gridDim.x * blockDim.x;
    for (int i = blockIdx.x*blockDim.x + threadIdx.x; i < TOT; i += stride) {
        if (i < XBN) {
            int grow = i >> 8, k = i & 255;
            int b = grow >> 11, n = grow & (NN-1);
            size_t base = ((size_t)b*LP1 + 1 + 2*n)*CC + k;
            float v = 0.5f*(feats[base] + feats[base + CC]);
            xb[i] = __float2bfloat16(v);
        } else if (i < XBN + WTN) {
            int j = i - XBN;
            int c = j >> 8, k = j & 255;
            float v;
            if (c < HR)                 v = Wq[k*HR + c] * HEAD_SCALE;
            else if (c < 2*HR)          v = Wk[k*HR + (c-HR)];
            else if (c < 2*HR+PDim)     v = Wpi[k*PDim + (c-2*HR)];
            else if (c < 2*HR+2*PDim)   v = Wpj[k*PDim + (c-2*HR-PDim)];
            else if (c == 416)          v = Wd[k];
            else                        v = 0.f;
            WT[j] = __float2bfloat16(v);
        } else {
            int j = i - XBN - WTN;
            unsigned* arr = (j < PADN) ? Ppad : Rpad;
            int q = (j < PADN) ? j : j - PADN;
            int row = q / 24, cu = q % 24;
            arr[row*128 + 104 + cu] = 0u;   // elems [208,256) of each K=256 row
        }
    }
}

// ---------------- KA: projection GEMM ----------------
// (16384 x 256) x (256 x 448) -> routed epilogue into P, R (bf16) and d (f32).
// Block: 64 rows x 448 cols; wave w handles all 64 rows x cols [w*112, w*112+112).
__global__ __launch_bounds__(256, 1) void ka_proj(
    const __hip_bfloat16* __restrict__ xb, const __hip_bfloat16* __restrict__ WT,
    const float* __restrict__ bpi, const float* __restrict__ bpj,
    const float* __restrict__ bd, const float* __restrict__ alpha_pair,
    __hip_bfloat16* __restrict__ P, __hip_bfloat16* __restrict__ R,
    float* __restrict__ dvec)
{
    int t = threadIdx.x;
    int lane = t & 63;
    int w = t >> 6;
    int l15 = lane & 15, lg = lane >> 4;
    int row0 = blockIdx.x * 64;

    const __hip_bfloat16* pA[4];
    const __hip_bfloat16* pB[7];
#pragma unroll
    for (int mi = 0; mi < 4; ++mi)
        pA[mi] = xb + (size_t)(row0 + mi*16 + l15)*KP + lg*8;
#pragma unroll
    for (int ni = 0; ni < 7; ++ni)
        pB[ni] = WT + (size_t)(w*112 + ni*16 + l15)*KP + lg*8;

    f32x4 acc[4][7];
#pragma unroll
    for (int mi = 0; mi < 4; ++mi)
#pragma unroll
        for (int ni = 0; ni < 7; ++ni)
            acc[mi][ni] = (f32x4){0.f, 0.f, 0.f, 0.f};

#pragma unroll 2
    for (int kk = 0; kk < 8; ++kk) {
        short8 a[4], bb[7];
#pragma unroll
        for (int mi = 0; mi < 4; ++mi) a[mi] = *(const short8*)(pA[mi] + kk*32);
#pragma unroll
        for (int ni = 0; ni < 7; ++ni) bb[ni] = *(const short8*)(pB[ni] + kk*32);
#pragma unroll
        for (int mi = 0; mi < 4; ++mi)
#pragma unroll
            for (int ni = 0; ni < 7; ++ni)
                acc[mi][ni] = __builtin_amdgcn_mfma_f32_16x16x32_bf16(
                    a[mi], bb[ni], acc[mi][ni], 0, 0, 0);
    }

    float alpha_eff = fmaxf(alpha_pair[0], 0.f);
    float bd0 = bd[0];
#pragma unroll
    for (int mi = 0; mi < 4; ++mi) {
#pragma unroll
        for (int ni = 0; ni < 7; ++ni) {
            int c = w*112 + ni*16 + l15;
#pragma unroll
            for (int j = 0; j < 4; ++j) {
                int r = mi*16 + lg*4 + j;
                int grow = row0 + r;
                int b = grow >> 11, n = grow & (NN-1);
                size_t rb = ((size_t)b*NN + n)*KP;
                float v = acc[mi][ni][j];
                if (c < HR) {
                    P[rb + c] = __float2bfloat16(v);           // Q*HEAD_SCALE (baked in WT)
                } else if (c < 2*HR) {
                    R[rb + (c-HR)] = __float2bfloat16(v);      // K
                } else if (c < 2*HR+PDim) {
                    int pc = c - 2*HR;
                    P[rb + HR + pc] = __float2bfloat16(fmaxf(v + bpi[pc], 0.f) * alpha_eff);
                } else if (c < 2*HR+2*PDim) {
                    int pc = c - 2*HR - PDim;
                    R[rb + HR + pc] = __float2bfloat16(fmaxf(v + bpj[pc], 0.f));
                } else if (c == 416) {
                    dvec[(size_t)b*NN + n] = v + bd0;
                }
            }
        }
    }
}

// ---------------- KB: batched pair GEMM ----------------
// S[b] = P[b] (2048x256) x R[b]^T + diag(d), then * max(logit_scale, 0.01).
// Grid (16,16,8); block 128x128 tile, 4 waves, wave quadrant 64x64.
__global__ __launch_bounds__(256, 2) void kb_pair(
    const __hip_bfloat16* __restrict__ P, const __hip_bfloat16* __restrict__ R,
    const float* __restrict__ dvec, const float* __restrict__ logit_scale,
    float* __restrict__ out)
{
    int t = threadIdx.x;
    int lane = t & 63;
    int w = t >> 6;
    int wr = w >> 1, wc = w & 1;
    int l15 = lane & 15, lg = lane >> 4;
    int b  = blockIdx.z;
    int n0 = blockIdx.y * 128;
    int m0 = blockIdx.x * 128;

    const __hip_bfloat16* pA[4];
    const __hip_bfloat16* pB[4];
#pragma unroll
    for (int mi = 0; mi < 4; ++mi)
        pA[mi] = P + ((size_t)b*NN + n0 + wr*64 + mi*16 + l15)*KP + lg*8;
#pragma unroll
    for (int ni = 0; ni < 4; ++ni)
        pB[ni] = R + ((size_t)b*NN + m0 + wc*64 + ni*16 + l15)*KP + lg*8;

    f32x4 acc[4][4];
#pragma unroll
    for (int mi = 0; mi < 4; ++mi)
#pragma unroll
        for (int ni = 0; ni < 4; ++ni)
            acc[mi][ni] = (f32x4){0.f, 0.f, 0.f, 0.f};

#pragma unroll
    for (int kk = 0; kk < 8; ++kk) {
        short8 a[4], bb[4];
#pragma unroll
        for (int mi = 0; mi < 4; ++mi) a[mi] = *(const short8*)(pA[mi] + kk*32);
#pragma unroll
        for (int ni = 0; ni < 4; ++ni) bb[ni] = *(const short8*)(pB[ni] + kk*32);
#pragma unroll
        for (int mi = 0; mi < 4; ++mi)
#pragma unroll
            for (int ni = 0; ni < 4; ++ni)
                acc[mi][ni] = __builtin_amdgcn_mfma_f32_16x16x32_bf16(
                    a[mi], bb[ni], acc[mi][ni], 0, 0, 0);
    }

    float ls = fmaxf(logit_scale[0], 0.01f);
#pragma unroll
    for (int mi = 0; mi < 4; ++mi) {
#pragma unroll
        for (int ni = 0; ni < 4; ++ni) {
            int col = m0 + wc*64 + ni*16 + l15;
#pragma unroll
            for (int j = 0; j < 4; ++j) {
                int row = n0 + wr*64 + mi*16 + lg*4 + j;
                float v = acc[mi][ni][j];
                if (row == col) v += dvec[(size_t)b*NN + row];
                out[((size_t)b*NN + row)*NN + col] = v * ls;
            }
        }
    }
}

extern "C" void kernel_launch(void* const* d_in, const int* in_sizes, int n_in,
                              void* d_out, int out_size, void* d_ws, size_t ws_size,
                              hipStream_t stream)
{
    const float* feats = (const float*)d_in[0];
    const float* Wq    = (const float*)d_in[1];
    const float* Wk    = (const float*)d_in[2];
    const float* Wpi   = (const float*)d_in[3];
    const float* bpi   = (const float*)d_in[4];
    const float* Wpj   = (const float*)d_in[5];
    const float* bpj   = (const float*)d_in[6];
    const float* Wd    = (const float*)d_in[7];
    const float* bd    = (const float*)d_in[8];
    const float* alpha = (const float*)d_in[9];
    const float* lsc   = (const float*)d_in[10];

    char* ws = (char*)d_ws;
    __hip_bfloat16* xb = (__hip_bfloat16*)(ws);               // 8,388,608 B
    __hip_bfloat16* WT = (__hip_bfloat16*)(ws + 8388608);     //   229,376 B
    __hip_bfloat16* P  = (__hip_bfloat16*)(ws + 8617984);     // 8,388,608 B
    __hip_bfloat16* R  = (__hip_bfloat16*)(ws + 17006592);    // 8,388,608 B
    float*          dv = (float*)(ws + 25395200);             //    65,536 B

    k0_prep<<<2048, 256, 0, stream>>>(feats, Wq, Wk, Wpi, Wpj, Wd,
                                      xb, WT, (unsigned*)P, (unsigned*)R);
    ka_proj<<<256, 256, 0, stream>>>(xb, WT, bpi, bpj, bd, alpha, P, R, dv);
    kb_pair<<<dim3(16,16,8), 256, 0, stream>>>(P, R, dv, lsc, (float*)d_out);
}

// Round 2
// 79.318 us; speedup vs baseline: 1.4353x; 1.4353x over previous
//
#include <hip/hip_runtime.h>
#include <hip/hip_bf16.h>
#include <stdint.h>

typedef __attribute__((ext_vector_type(8))) short short8;
typedef __attribute__((ext_vector_type(4))) float f32x4;

#define NB 8
#define NN 2048
#define CC 256
#define LP1 4097
#define HR 192
#define PDim 16
#define KP 256
#define NPAD 448
#define HEAD_SCALE 0.17677669529663689f  /* 1/sqrt(32) */

#define GLOAD16(g, l) __builtin_amdgcn_global_load_lds( \
    (const __attribute__((address_space(1))) unsigned int*)(g), \
    (__attribute__((address_space(3))) unsigned int*)(l), 16, 0, 0)

// ---------------- K0: prep ----------------
__global__ __launch_bounds__(256) void k0_prep(
    const float* __restrict__ feats,
    const float* __restrict__ Wq, const float* __restrict__ Wk,
    const float* __restrict__ Wpi, const float* __restrict__ Wpj,
    const float* __restrict__ Wd,
    __hip_bfloat16* __restrict__ xb, __hip_bfloat16* __restrict__ WT,
    unsigned* __restrict__ Ppad, unsigned* __restrict__ Rpad)
{
    const int XBN  = NB*NN*CC;      // 4194304
    const int WTN  = NPAD*CC;       // 114688
    const int PADN = NB*NN*24;      // 393216 uint32 per array (cols 208..255)
    const int TOT  = XBN + WTN + 2*PADN;
    int stride = gridDim.x * blockDim.x;
    for (int i = blockIdx.x*blockDim.x + threadIdx.x; i < TOT; i += stride) {
        if (i < XBN) {
            int grow = i >> 8, k = i & 255;
            int b = grow >> 11, n = grow & (NN-1);
            size_t base = ((size_t)b*LP1 + 1 + 2*n)*CC + k;
            float v = 0.5f*(feats[base] + feats[base + CC]);
            xb[i] = __float2bfloat16(v);
        } else if (i < XBN + WTN) {
            int j = i - XBN;
            int c = j >> 8, k = j & 255;
            float v;
            if (c < HR)                 v = Wq[k*HR + c] * HEAD_SCALE;
            else if (c < 2*HR)          v = Wk[k*HR + (c-HR)];
            else if (c < 2*HR+PDim)     v = Wpi[k*PDim + (c-2*HR)];
            else if (c < 2*HR+2*PDim)   v = Wpj[k*PDim + (c-2*HR-PDim)];
            else if (c == 416)          v = Wd[k];
            else                        v = 0.f;
            WT[j] = __float2bfloat16(v);
        } else {
            int j = i - XBN - WTN;
            unsigned* arr = (j < PADN) ? Ppad : Rpad;
            int q = (j < PADN) ? j : j - PADN;
            int row = q / 24, cu = q % 24;
            arr[row*128 + 104 + cu] = 0u;   // elems [208,256) of each K=256 row
        }
    }
}

// ---------------- KA: projection GEMM ----------------
// (16384 x 256) x (256 x 448). Block = 32 rows x 448 cols, 512 blocks (2/CU).
// Wave w: 32 rows x cols [w*112, w*112+112) -> acc 2x7.
__global__ __launch_bounds__(256, 4) void ka_proj(
    const __hip_bfloat16* __restrict__ xb, const __hip_bfloat16* __restrict__ WT,
    const float* __restrict__ bpi, const float* __restrict__ bpj,
    const float* __restrict__ bd, const float* __restrict__ alpha_pair,
    __hip_bfloat16* __restrict__ P, __hip_bfloat16* __restrict__ R,
    float* __restrict__ dvec)
{
    int t = threadIdx.x;
    int lane = t & 63;
    int w = t >> 6;
    int l15 = lane & 15, lg = lane >> 4;
    int row0 = blockIdx.x * 32;

    const __hip_bfloat16* pA[2];
    const __hip_bfloat16* pB[7];
#pragma unroll
    for (int mi = 0; mi < 2; ++mi)
        pA[mi] = xb + (size_t)(row0 + mi*16 + l15)*KP + lg*8;
#pragma unroll
    for (int ni = 0; ni < 7; ++ni)
        pB[ni] = WT + (size_t)(w*112 + ni*16 + l15)*KP + lg*8;

    f32x4 acc[2][7];
#pragma unroll
    for (int mi = 0; mi < 2; ++mi)
#pragma unroll
        for (int ni = 0; ni < 7; ++ni)
            acc[mi][ni] = (f32x4){0.f, 0.f, 0.f, 0.f};

#pragma unroll
    for (int kk = 0; kk < 8; ++kk) {
        short8 a[2], bb[7];
#pragma unroll
        for (int mi = 0; mi < 2; ++mi) a[mi] = *(const short8*)(pA[mi] + kk*32);
#pragma unroll
        for (int ni = 0; ni < 7; ++ni) bb[ni] = *(const short8*)(pB[ni] + kk*32);
#pragma unroll
        for (int mi = 0; mi < 2; ++mi)
#pragma unroll
            for (int ni = 0; ni < 7; ++ni)
                acc[mi][ni] = __builtin_amdgcn_mfma_f32_16x16x32_bf16(
                    a[mi], bb[ni], acc[mi][ni], 0, 0, 0);
    }

    float alpha_eff = fmaxf(alpha_pair[0], 0.f);
    float bd0 = bd[0];
#pragma unroll
    for (int mi = 0; mi < 2; ++mi) {
#pragma unroll
        for (int ni = 0; ni < 7; ++ni) {
            int c = w*112 + ni*16 + l15;
#pragma unroll
            for (int j = 0; j < 4; ++j) {
                int r = mi*16 + lg*4 + j;
                int grow = row0 + r;
                int b = grow >> 11, n = grow & (NN-1);
                size_t rb = ((size_t)b*NN + n)*KP;
                float v = acc[mi][ni][j];
                if (c < HR) {
                    P[rb + c] = __float2bfloat16(v);           // Q*HEAD_SCALE (in WT)
                } else if (c < 2*HR) {
                    R[rb + (c-HR)] = __float2bfloat16(v);      // K
                } else if (c < 2*HR+PDim) {
                    int pc = c - 2*HR;
                    P[rb + HR + pc] = __float2bfloat16(fmaxf(v + bpi[pc], 0.f) * alpha_eff);
                } else if (c < 2*HR+2*PDim) {
                    int pc = c - 2*HR - PDim;
                    R[rb + HR + pc] = __float2bfloat16(fmaxf(v + bpj[pc], 0.f));
                } else if (c == 416) {
                    dvec[(size_t)b*NN + n] = v + bd0;
                }
            }
        }
    }
}

// ---------------- KB: batched pair GEMM, LDS double-buffered ----------------
// S[b] = P[b] (2048x256) x R[b]^T + diag(d), * max(logit_scale,0.01).
// 128x128 tile, BK=32, 4 waves (64x64 quadrant each), dbuf LDS 32 KB.
// Staging: global_load_lds w=16, linear LDS dest; bank swizzle via
// pre-swizzled global source (colbyte ^= (row&3)<<4), same XOR on ds_read.
__global__ __launch_bounds__(256, 4) void kb_pair(
    const __hip_bfloat16* __restrict__ P, const __hip_bfloat16* __restrict__ R,
    const float* __restrict__ dvec, const float* __restrict__ logit_scale,
    float* __restrict__ out)
{
    __shared__ __hip_bfloat16 ldsA[2][128*32];
    __shared__ __hip_bfloat16 ldsB[2][128*32];

    int t = threadIdx.x;
    int lane = t & 63;
    int w = t >> 6;
    int wr = w >> 1, wc = w & 1;
    int l15 = lane & 15, lg = lane >> 4;
    int b  = blockIdx.z;
    int n0 = blockIdx.y * 128;   // output rows (P rows)
    int m0 = blockIdx.x * 128;   // output cols (R rows)

    // staging source addrs (pre-swizzled). inst i: LDS byte = i*4096 + t*16
    // -> row = i*64 + (t>>2), colb = (t&3)*16; src colb = colb ^ ((row&3)<<4)
    const char* srcA[2];
    const char* srcB[2];
#pragma unroll
    for (int i = 0; i < 2; ++i) {
        int row   = i*64 + (t >> 2);
        int scolb = ((t & 3) << 4) ^ ((row & 3) << 4);
        srcA[i] = (const char*)(P + ((size_t)b*NN + n0 + row)*KP) + scolb;
        srcB[i] = (const char*)(R + ((size_t)b*NN + m0 + row)*KP) + scolb;
    }
    // wave-uniform LDS dest base (+ lane*16 applied by HW)
    int ldst = w * 1024;

    // ds_read byte offsets (swizzled): row*64 + 16*(lg ^ (row&3)), + frag*1024
    int abyte = (wr*64 + l15)*64 + (((lg) ^ (l15 & 3)) << 4);
    int bbyte = (wc*64 + l15)*64 + (((lg) ^ (l15 & 3)) << 4);

    f32x4 acc[4][4];
#pragma unroll
    for (int mi = 0; mi < 4; ++mi)
#pragma unroll
        for (int ni = 0; ni < 4; ++ni)
            acc[mi][ni] = (f32x4){0.f, 0.f, 0.f, 0.f};

    // prologue: stage K-step 0 into buf 0
#pragma unroll
    for (int i = 0; i < 2; ++i) {
        GLOAD16(srcA[i], (char*)(&ldsA[0][0]) + i*4096 + ldst);
        GLOAD16(srcB[i], (char*)(&ldsB[0][0]) + i*4096 + ldst);
    }

    int buf = 0;
#pragma unroll
    for (int s = 0; s < 8; ++s) {
        __syncthreads();   // staging of buf complete; prior reads of buf^1 done
        if (s < 7) {
            size_t kof = (size_t)(s + 1) * 64;   // next 32-elem K chunk (bytes)
#pragma unroll
            for (int i = 0; i < 2; ++i) {
                GLOAD16(srcA[i] + kof, (char*)(&ldsA[buf ^ 1][0]) + i*4096 + ldst);
                GLOAD16(srcB[i] + kof, (char*)(&ldsB[buf ^ 1][0]) + i*4096 + ldst);
            }
        }
        short8 a[4], bb[4];
#pragma unroll
        for (int mi = 0; mi < 4; ++mi)
            a[mi] = *(const short8*)((const char*)(&ldsA[buf][0]) + abyte + mi*1024);
#pragma unroll
        for (int ni = 0; ni < 4; ++ni)
            bb[ni] = *(const short8*)((const char*)(&ldsB[buf][0]) + bbyte + ni*1024);
#pragma unroll
        for (int mi = 0; mi < 4; ++mi)
#pragma unroll
            for (int ni = 0; ni < 4; ++ni)
                acc[mi][ni] = __builtin_amdgcn_mfma_f32_16x16x32_bf16(
                    a[mi], bb[ni], acc[mi][ni], 0, 0, 0);
        buf ^= 1;
    }

    float ls = fmaxf(logit_scale[0], 0.01f);
#pragma unroll
    for (int mi = 0; mi < 4; ++mi) {
#pragma unroll
        for (int ni = 0; ni < 4; ++ni) {
            int col = m0 + wc*64 + ni*16 + l15;
#pragma unroll
            for (int j = 0; j < 4; ++j) {
                int row = n0 + wr*64 + mi*16 + lg*4 + j;
                float v = acc[mi][ni][j];
                if (row == col) v += dvec[(size_t)b*NN + row];
                out[((size_t)b*NN + row)*NN + col] = v * ls;
            }
        }
    }
}

extern "C" void kernel_launch(void* const* d_in, const int* in_sizes, int n_in,
                              void* d_out, int out_size, void* d_ws, size_t ws_size,
                              hipStream_t stream)
{
    const float* feats = (const float*)d_in[0];
    const float* Wq    = (const float*)d_in[1];
    const float* Wk    = (const float*)d_in[2];
    const float* Wpi   = (const float*)d_in[3];
    const float* bpi   = (const float*)d_in[4];
    const float* Wpj   = (const float*)d_in[5];
    const float* bpj   = (const float*)d_in[6];
    const float* Wd    = (const float*)d_in[7];
    const float* bd    = (const float*)d_in[8];
    const float* alpha = (const float*)d_in[9];
    const float* lsc   = (const float*)d_in[10];

    char* ws = (char*)d_ws;
    __hip_bfloat16* xb = (__hip_bfloat16*)(ws);               // 8,388,608 B
    __hip_bfloat16* WT = (__hip_bfloat16*)(ws + 8388608);     //   229,376 B
    __hip_bfloat16* P  = (__hip_bfloat16*)(ws + 8617984);     // 8,388,608 B
    __hip_bfloat16* R  = (__hip_bfloat16*)(ws + 17006592);    // 8,388,608 B
    float*          dv = (float*)(ws + 25395200);             //    65,536 B

    k0_prep<<<2048, 256, 0, stream>>>(feats, Wq, Wk, Wpi, Wpj, Wd,
                                      xb, WT, (unsigned*)P, (unsigned*)R);
    ka_proj<<<512, 256, 0, stream>>>(xb, WT, bpi, bpj, bd, alpha, P, R, dv);
    kb_pair<<<dim3(16,16,8), 256, 0, stream>>>(P, R, dv, lsc, (float*)d_out);
}